// Round 6
// baseline (181.086 us; speedup 1.0000x reference)
//
#include <hip/hip_runtime.h>
#include <hip/hip_bf16.h>

typedef __hip_bfloat16 bf16;
typedef _Float16 f16;
typedef __attribute__((ext_vector_type(8))) __bf16 bf16x8;
typedef __attribute__((ext_vector_type(8))) _Float16 f16x8;
typedef __attribute__((ext_vector_type(4))) _Float16 f16x4;
typedef __attribute__((ext_vector_type(4))) float floatx4;
typedef __attribute__((ext_vector_type(16))) float floatx16;

#define T_SEQ 2048
#define EMB   1024
#define LAMBDA_INIT 0.35550906759096926f

// round-to-nearest-even fp32 -> bf16
__device__ __forceinline__ bf16 f2bf(float f) {
  unsigned u;
  __builtin_memcpy(&u, &f, 4);
  u += 0x7FFF + ((u >> 16) & 1);
  unsigned short h = (unsigned short)(u >> 16);
  bf16 r;
  __builtin_memcpy(&r, &h, 2);
  return r;
}

// v_cvt_pk_bf16_f32: d[15:0]=bf16(lo), d[31:16]=bf16(hi)
__device__ __forceinline__ int cvtpk_bf16(float lo, float hi) {
  int r;
  asm("v_cvt_pk_bf16_f32 %0, %1, %2" : "=v"(r) : "v"(lo), "v"(hi));
  return r;
}

// v_permlane32_swap_b32: swaps a's upper-32-lane half with b's lower half.
__device__ __forceinline__ void permswap(int& a, int& b) {
  asm volatile("v_permlane32_swap_b32 %0, %1" : "+v"(a), "+v"(b));
}

__device__ __forceinline__ void gl_lds16(const void* g, void* l) {
  __builtin_amdgcn_global_load_lds((const __attribute__((address_space(1))) void*)g,
                                   (__attribute__((address_space(3))) void*)l, 16, 0, 0);
}

__device__ __forceinline__ floatx4 mfma_h(f16x8 a, f16x8 b, floatx4 c) {
  return __builtin_amdgcn_mfma_f32_16x16x32_f16(a, b, c, 0, 0, 0);
}
__device__ __forceinline__ floatx16 mfma32_h(f16x8 a, f16x8 b, floatx16 c) {
  return __builtin_amdgcn_mfma_f32_32x32x16_f16(a, b, c, 0, 0, 0);
}
__device__ __forceinline__ floatx16 mfma32_bf(bf16x8 a, bf16x8 b, floatx16 c) {
  return __builtin_amdgcn_mfma_f32_32x32x16_bf16(a, b, c, 0, 0, 0);
}

// =====================================================================
// fp32 -> fp16 conversion for x, Wq, Wk, Wv, Wo.
// =====================================================================
__global__ __launch_bounds__(256) void convert_kernel(
    const float* __restrict__ x,  const float* __restrict__ wq,
    const float* __restrict__ wk, const float* __restrict__ wv,
    const float* __restrict__ wo,
    f16* __restrict__ xf, f16* __restrict__ wqf, f16* __restrict__ wkf,
    f16* __restrict__ wvf, f16* __restrict__ wof)
{
  int b = blockIdx.x;
  const float* src; f16* dst; long off;
  if      (b < 2048) { src = x;  dst = xf;  off = (long)b * 1024; }
  else if (b < 3072) { src = wq; dst = wqf; off = (long)(b - 2048) * 1024; }
  else if (b < 4096) { src = wk; dst = wkf; off = (long)(b - 3072) * 1024; }
  else if (b < 5120) { src = wv; dst = wvf; off = (long)(b - 4096) * 1024; }
  else               { src = wo; dst = wof; off = (long)(b - 5120) * 1024; }
  long i = off + threadIdx.x * 4;
  float4 v = *(const float4*)(src + i);
  f16x4 o;
  o.x = (f16)v.x; o.y = (f16)v.y; o.z = (f16)v.z; o.w = (f16)v.w;
  *(f16x4*)(dst + i) = o;
}

// =====================================================================
// OLD fp16 NT GEMM, 64x128 tile (kept for out_gemm only, MODE 1).
// =====================================================================
template <int MODE>
__device__ __forceinline__ void gemm64x128_f16(
    const f16* __restrict__ A_, const f16* __restrict__ B_,
    void* C0v, int K, int ldc, int m0, int n0, char* smem)
{
  f16* As = (f16*)smem;              // 64 x 64 swz (8 KB)
  f16* Bs = (f16*)(smem + 8192);     // 128 x 64 swz (16 KB)
  const int tid  = threadIdx.x;
  const int wave = tid >> 6, lane = tid & 63, quad = lane >> 4, l16 = lane & 15;
  const int mo = (wave & 1) << 5;
  const int no = (wave >> 1) << 6;

  floatx4 acc[2][4];
  #pragma unroll
  for (int i = 0; i < 2; i++)
    #pragma unroll
    for (int j = 0; j < 4; j++) { acc[i][j][0]=0.f; acc[i][j][1]=0.f; acc[i][j][2]=0.f; acc[i][j][3]=0.f; }

  const int srow = tid >> 3;
  const int ch   = (tid & 7) ^ (srow & 7);
  const long aoff = (long)(m0 + srow) * K + ch * 8;
  const long boff = (long)(n0 + srow) * K + ch * 8;
  const int wb = wave << 10;

  for (int k0 = 0; k0 < K; k0 += 64) {
    #pragma unroll
    for (int rr = 0; rr < 2; rr++)
      gl_lds16(A_ + aoff + k0 + (long)rr * 32 * K, smem + wb + rr * 4096);
    #pragma unroll
    for (int rr = 0; rr < 4; rr++)
      gl_lds16(B_ + boff + k0 + (long)rr * 32 * K, smem + 8192 + wb + rr * 4096);
    __syncthreads();
    #pragma unroll
    for (int kt = 0; kt < 2; kt++) {
      f16x8 a[2], b[4];
      #pragma unroll
      for (int i = 0; i < 2; i++) {
        int m = mo + i * 16 + l16;
        a[i] = *(const f16x8*)(As + m * 64 + ((((kt << 2) | quad) ^ (m & 7)) << 3));
      }
      #pragma unroll
      for (int j = 0; j < 4; j++) {
        int n = no + j * 16 + l16;
        b[j] = *(const f16x8*)(Bs + n * 64 + ((((kt << 2) | quad) ^ (n & 7)) << 3));
      }
      #pragma unroll
      for (int i = 0; i < 2; i++)
        #pragma unroll
        for (int j = 0; j < 4; j++)
          acc[i][j] = mfma_h(a[i], b[j], acc[i][j]);
    }
    __syncthreads();
  }

  if (MODE == 1) {
    #pragma unroll
    for (int i = 0; i < 2; i++)
      #pragma unroll
      for (int j = 0; j < 4; j++)
        #pragma unroll
        for (int r = 0; r < 4; r++) {
          int row = m0 + mo + i * 16 + quad * 4 + r;
          int col = n0 + no + j * 16 + l16;
          ((float*)C0v)[(long)row * ldc + col] = acc[i][j][r];
        }
  }
}

// =====================================================================
// NEW fp16 NT GEMM, 128x128 tile, BK=64, m97-class MFMA density.
// 4 waves; wave owns 32 rows x 128 cols (acc[2][8], 32 MFMA/K-step).
// Single-barrier schedule (round-5-verified): vmcnt(0) -> s_barrier ->
// ALL 20 ds_read_b128 -> regs -> issue 8 gl_lds (next tile) -> MFMA.
// LDS: dbuf 2 x (A 16KB | B 16KB) = 64KB. 2 blocks/CU.
// MODE 2 = RoPE-Q epilogue (fold 0.125) -> fp16; MODE 3 = RoPE-K (inv)
// MODE 0 = bf16 out (V).
// =====================================================================
template <int MODE>
__device__ __forceinline__ void gemm128x128_f16(
    const f16* __restrict__ A_, const f16* __restrict__ B_,
    void* C0v, int K, int ldc, int m0, int n0, char* smem)
{
  const int tid  = threadIdx.x;
  const int wave = tid >> 6, lane = tid & 63, quad = lane >> 4, l16 = lane & 15;
  const int mo = wave << 5;

  floatx4 acc[2][8];
  #pragma unroll
  for (int i = 0; i < 2; i++)
    #pragma unroll
    for (int j = 0; j < 8; j++) { acc[i][j][0]=0.f; acc[i][j][1]=0.f; acc[i][j][2]=0.f; acc[i][j][3]=0.f; }

  const int srow = tid >> 3;              // 0..31
  const int ch   = (tid & 7) ^ (srow & 7);
  const long aoff = (long)(m0 + srow) * K + ch * 8;
  const long boff = (long)(n0 + srow) * K + ch * 8;
  const int wb = wave << 10;              // per-wave 1KB slot in each 4KB issue

  // prologue: stage K-step 0 into buffer 0
  #pragma unroll
  for (int j = 0; j < 4; j++) {
    gl_lds16(A_ + aoff + (long)j * 32 * K, smem + j * 4096 + wb);
    gl_lds16(B_ + boff + (long)j * 32 * K, smem + 16384 + j * 4096 + wb);
  }

  for (int k0 = 0; k0 < K; k0 += 64) {
    const int cur = (k0 >> 6) & 1;
    const char* sb = smem + cur * 32768;

    // own tile-i loads issued a full iteration ago -> no stall
    asm volatile("s_waitcnt vmcnt(0)" ::: "memory");
    asm volatile("s_barrier" ::: "memory");

    const f16* As = (const f16*)sb;
    const f16* Bs = (const f16*)(sb + 16384);

    // ---- register staging: ALL ds_reads before any gl_lds issue ----
    f16x8 a[2][2], b[2][8];
    #pragma unroll
    for (int kt = 0; kt < 2; kt++) {
      #pragma unroll
      for (int i = 0; i < 2; i++) {
        int m = mo + i * 16 + l16;
        a[kt][i] = *(const f16x8*)(As + m * 64 + ((((kt << 2) | quad) ^ (m & 7)) << 3));
      }
      #pragma unroll
      for (int j = 0; j < 8; j++) {
        int n = j * 16 + l16;
        b[kt][j] = *(const f16x8*)(Bs + n * 64 + ((((kt << 2) | quad) ^ (n & 7)) << 3));
      }
    }

    // ---- prefetch issue ----
    if (k0 + 64 < K) {
      char* nb = smem + (cur ^ 1) * 32768;
      #pragma unroll
      for (int j = 0; j < 4; j++) {
        gl_lds16(A_ + aoff + k0 + 64 + (long)j * 32 * K, nb + j * 4096 + wb);
        gl_lds16(B_ + boff + k0 + 64 + (long)j * 32 * K, nb + 16384 + j * 4096 + wb);
      }
    }

    // ---- register-only MFMA ----
    #pragma unroll
    for (int kt = 0; kt < 2; kt++)
      #pragma unroll
      for (int i = 0; i < 2; i++)
        #pragma unroll
        for (int j = 0; j < 8; j++)
          acc[i][j] = mfma_h(a[kt][i], b[kt][j], acc[i][j]);
  }
  __syncthreads();   // before epilogue reuses smem

  unsigned short* E = (unsigned short*)smem;   // 128x128 2-byte = 32 KB
  #pragma unroll
  for (int i = 0; i < 2; i++)
    #pragma unroll
    for (int j = 0; j < 8; j++)
      #pragma unroll
      for (int r = 0; r < 4; r++) {
        int row = mo + i * 16 + quad * 4 + r;
        int col = j * 16 + l16;
        float v = acc[i][j][r];
        unsigned short bits;
        if (MODE == 0) {
          bf16 t = f2bf(v);
          __builtin_memcpy(&bits, &t, 2);
        } else {
          float p = __shfl_xor(v, 1, 64);
          int gcol = n0 + col;
          int d = gcol & 63;
          float fr = (float)(m0 + row) * __expf((float)(d >> 1) * -0.28782313662425574f);
          float sn, cs;
          sincosf(fr, &sn, &cs);
          float rot = (gcol & 1) ? fmaf(v, cs, p * sn) : fmaf(v, cs, -p * sn);
          float power = (float)(m0 + row - 1024) * (1.0f / 512.0f);
          if (MODE == 3) power = -power;
          float sv = fmaf(2.0f, (float)(d & 31), 25.6f) * (1.0f / 89.6f);
          float s = __expf(power * __logf(sv));
          float ov = rot * s;
          if (MODE == 2) ov *= 0.125f;
          f16 t = (f16)ov;
          __builtin_memcpy(&bits, &t, 2);
        }
        E[row * 128 + col] = bits;
      }
  __syncthreads();
  const int rr0 = tid >> 4;
  const int c8  = (tid & 15) * 8;
  #pragma unroll
  for (int p2 = 0; p2 < 8; p2++) {
    int row = p2 * 16 + rr0;
    *(uint4*)((unsigned short*)C0v + (long)(m0 + row) * ldc + n0 + c8) =
        *(const uint4*)(E + row * 128 + c8);
  }
}

__global__ __launch_bounds__(256, 2) void qkv_gemm(
    const f16* __restrict__ xf,
    const f16* __restrict__ wqf, const f16* __restrict__ wkf,
    const f16* __restrict__ wvf,
    f16* __restrict__ qf, f16* __restrict__ kf, bf16* __restrict__ vt)
{
  __shared__ char smem[65536];
  int bid = blockIdx.x;
  if (bid < 128) {
    gemm128x128_f16<2>(xf, wqf, qf, 1024, 1024, (bid >> 3) * 128, (bid & 7) * 128, smem);
  } else if (bid < 256) {
    bid -= 128;
    gemm128x128_f16<3>(xf, wkf, kf, 1024, 1024, (bid >> 3) * 128, (bid & 7) * 128, smem);
  } else {
    bid -= 256;
    gemm128x128_f16<0>(wvf, xf, vt, 1024, 2048, (bid >> 4) * 128, (bid & 15) * 128, smem);
  }
}

__global__ __launch_bounds__(256) void out_gemm(const f16* __restrict__ attn,
                                                const f16* __restrict__ Wo,
                                                float* __restrict__ out)
{
  __shared__ char smem[24576];
  gemm64x128_f16<1>(attn, Wo, out, 1024, 1024,
                    (blockIdx.x >> 3) * 64, (blockIdx.x & 7) * 128, smem);
}

// =====================================================================
// Differential flash attention — register-staged single-barrier edition
// (round-5 structure, unchanged; best measured 51.0 µs).
// =====================================================================
__global__ __launch_bounds__(256) void diff_attn(
    const f16* __restrict__ qf_, const f16* __restrict__ kf_,
    const bf16* __restrict__ vt,
    const float* __restrict__ lq1, const float* __restrict__ lk1,
    const float* __restrict__ lq2, const float* __restrict__ lk2,
    f16* __restrict__ attn)
{
  __shared__ char smem[65536];
  // buf b at b*32768: K0 @0 (8KB) | K1 @8192 (8KB) | V @16384 (16KB)
  const int tid  = threadIdx.x;
  const int wave = tid >> 6, lane = tid & 63;
  const int l32 = lane & 31, lh = lane >> 5;
  const int h  = blockIdx.x & 7;         // head pair — XCD-affine
  const int qb = blockIdx.x >> 3;        // q block 0..63 (32 rows each)
  const int hl = wave >> 1;              // head in pair
  const int ws = wave & 1;               // key-half of this wave
  const int hh = h * 2 + hl;
  const int t0 = qb * 32;

  float a1 = lq1[lane] * lk1[lane];
  float a2 = lq2[lane] * lk2[lane];
  #pragma unroll
  for (int off = 1; off < 64; off <<= 1) {
    a1 += __shfl_xor(a1, off, 64);
    a2 += __shfl_xor(a2, off, 64);
  }
  const float lam = __expf(a1) - __expf(a2) + LAMBDA_INIT;

  // Q B-frags (32 rows x 64 d): n=query=l32, k = kt*16 + lh*8 + j
  f16x8 qfr[4];
  {
    const f16* qrow = qf_ + (long)(t0 + l32) * EMB + hh * 64 + lh * 8;
    #pragma unroll
    for (int kt = 0; kt < 4; kt++) qfr[kt] = *(const f16x8*)(qrow + kt * 16);
  }

  floatx16 o[4];   // nt over Dv=128, un-normalized accumulation
  #pragma unroll
  for (int nt = 0; nt < 4; nt++)
    #pragma unroll
    for (int r = 0; r < 16; r++) o[nt][r] = 0.f;
  // denominator partials: 4-way tree to cut the serial add chain
  float lr0 = 0.f, lr1 = 0.f, lr2 = 0.f, lr3 = 0.f;

  // staging: waves 0,1 -> K0,K1; waves 2,3 -> V halves
  const int srow = lane >> 3;
  const int ch   = (lane & 7) ^ srow;
  const f16*  kgp = kf_ + (long)(h * 2 + ws) * 64 + (long)srow * EMB + ch * 8;
  const bf16* vgp = vt + (long)(h * 128 + (wave - 2) * 64 + srow) * T_SEQ + ch * 8;
  const int kofs = wave * 8192;                 // waves 0,1
  const int vofs = 16384 + (wave - 2) * 8192;   // waves 2,3

  // prologue: stage tile 0 into buffer 0
  if (wave < 2) {
    #pragma unroll
    for (int j = 0; j < 8; j++)
      gl_lds16(kgp + (long)j * 8 * EMB, smem + kofs + j * 1024);
  } else {
    #pragma unroll
    for (int j = 0; j < 8; j++)
      gl_lds16(vgp + (long)j * 8 * T_SEQ, smem + vofs + j * 1024);
  }

  for (int kb = 0; kb < T_SEQ; kb += 64) {
    const int cur = (kb >> 6) & 1;
    const char* sb = smem + cur * 32768;

    // own tile-i loads were issued a full iteration ago -> no stall
    asm volatile("s_waitcnt vmcnt(0)" ::: "memory");
    // all waves' tile-i loads landed; all waves left iter i-1
    asm volatile("s_barrier" ::: "memory");

    const f16*  Ks  = (const f16*)(sb + hl * 8192);
    const bf16* Vsb = (const bf16*)(sb + 16384);

    // ---- register staging: ALL ds_reads before any gl_lds issue ----
    f16x8 kfr[4];
    #pragma unroll
    for (int kt = 0; kt < 4; kt++) {
      int krow = ws * 32 + l32;
      int c = kt * 2 + lh;
      kfr[kt] = *(const f16x8*)(Ks + krow * 64 + ((c ^ (krow & 7)) << 3));
    }
    bf16x8 vfr[4][2];
    #pragma unroll
    for (int nt = 0; nt < 4; nt++) {
      #pragma unroll
      for (int kt = 0; kt < 2; kt++) {
        int vrow = nt * 32 + l32;
        int c = ws * 4 + kt * 2 + lh;
        vfr[nt][kt] = *(const bf16x8*)(Vsb + vrow * 64 + ((c ^ (vrow & 7)) << 3));
      }
    }

    // ---- prefetch issue (after all ds_reads in program order) ----
    if (kb + 64 < T_SEQ) {
      char* nb = smem + (cur ^ 1) * 32768;
      if (wave < 2) {
        #pragma unroll
        for (int j = 0; j < 8; j++)
          gl_lds16(kgp + (long)(kb + 64) * EMB + (long)j * 8 * EMB,
                   nb + kofs + j * 1024);
      } else {
        #pragma unroll
        for (int j = 0; j < 8; j++)
          gl_lds16(vgp + (kb + 64) + (long)j * 8 * T_SEQ,
                   nb + vofs + j * 1024);
      }
    }

    // ---- compute: pure registers from here ----
    // QK^T swapped: A=K (m=key=l32 of own half), B=Q (n=query=l32)
    floatx16 s;
    #pragma unroll
    for (int r = 0; r < 16; r++) s[r] = 0.f;
    #pragma unroll
    for (int kt = 0; kt < 4; kt++)
      s = mfma32_h(kfr[kt], qfr[kt], s);
    // static-offset softmax; denominator partials in a 4-way tree
    #pragma unroll
    for (int r = 0; r < 4; r++) {
      float p0 = __builtin_amdgcn_exp2f(
          fmaf(s[r], 1.4426950408889634f, -17.312340490667562f));
      float p1 = __builtin_amdgcn_exp2f(
          fmaf(s[r + 4], 1.4426950408889634f, -17.312340490667562f));
      float p2 = __builtin_amdgcn_exp2f(
          fmaf(s[r + 8], 1.4426950408889634f, -17.312340490667562f));
      float p3 = __builtin_amdgcn_exp2f(
          fmaf(s[r + 12], 1.4426950408889634f, -17.312340490667562f));
      s[r] = p0; s[r + 4] = p1; s[r + 8] = p2; s[r + 12] = p3;
      lr0 += p0; lr1 += p1; lr2 += p2; lr3 += p3;
    }
    // in-register P -> bf16 A-frags (cvt_pk + permlane32_swap)
    bf16x8 pf[2];
    #pragma unroll
    for (int kt = 0; kt < 2; kt++) {
      const int b0 = kt * 8;
      int w0 = cvtpk_bf16(s[b0 + 0], s[b0 + 1]);
      int w1 = cvtpk_bf16(s[b0 + 2], s[b0 + 3]);
      int w2 = cvtpk_bf16(s[b0 + 4], s[b0 + 5]);
      int w3 = cvtpk_bf16(s[b0 + 6], s[b0 + 7]);
      permswap(w0, w2);
      permswap(w1, w3);
      union { int i[4]; bf16x8 v; } u;
      u.i[0] = w0; u.i[1] = w1; u.i[2] = w2; u.i[3] = w3;
      pf[kt] = u.v;
    }
    // PV: O += P V over own keys (register V frags)
    #pragma unroll
    for (int nt = 0; nt < 4; nt++) {
      #pragma unroll
      for (int kt = 0; kt < 2; kt++)
        o[nt] = mfma32_bf(pf[kt], vfr[nt][kt], o[nt]);
    }
  }
  __syncthreads();   // loop exit sync before epilogue overwrites smem

  float lr = (lr0 + lr1) + (lr2 + lr3);
  // merge lh halves: lrw = this wave's full 32-key denominator for query l32
  float lrw = lr + __shfl_xor(lr, 32, 64);

  float* Cb = (float*)smem;                  // 2 heads x 32x128 fp32 = 32KB
  float* Lb = (float*)(smem + 32768);        // 128 denominator partials

  // phase 1: key-half ws==1 publishes raw O; all waves publish lrw
  if (ws == 1) {
    #pragma unroll
    for (int r = 0; r < 16; r++) {
      int m = (r & 3) + 8 * (r >> 2) + 4 * lh;
      #pragma unroll
      for (int nt = 0; nt < 4; nt++)
        Cb[hl * 4096 + m * 128 + nt * 32 + l32] = o[nt][r];
    }
  }
  if (lh == 0) Lb[ws * 64 + hl * 32 + l32] = lrw;
  __syncthreads();
  // phase 2: ws==0 merges halves and normalizes
  if (ws == 0) {
    #pragma unroll
    for (int r = 0; r < 16; r++) {
      int m = (r & 3) + 8 * (r >> 2) + 4 * lh;
      float inv = 1.0f / (Lb[hl * 32 + m] + Lb[64 + hl * 32 + m]);
      #pragma unroll
      for (int nt = 0; nt < 4; nt++)
        o[nt][r] = (o[nt][r] + Cb[hl * 4096 + m * 128 + nt * 32 + l32]) * inv;
    }
  }
  __syncthreads();
  // phase 3: head1 publishes normalized O1
  if (hl == 1 && ws == 0) {
    #pragma unroll
    for (int r = 0; r < 16; r++) {
      int m = (r & 3) + 8 * (r >> 2) + 4 * lh;
      #pragma unroll
      for (int nt = 0; nt < 4; nt++)
        Cb[4096 + m * 128 + nt * 32 + l32] = o[nt][r];
    }
  }
  __syncthreads();
  // phase 4: head0 does diff + rms-norm + store
  if (hl == 0 && ws == 0) {
    float ss[16];
    #pragma unroll
    for (int r = 0; r < 16; r++) {
      int m = (r & 3) + 8 * (r >> 2) + 4 * lh;
      ss[r] = 0.f;
      #pragma unroll
      for (int nt = 0; nt < 4; nt++) {
        float v = o[nt][r] - lam * Cb[4096 + m * 128 + nt * 32 + l32];
        o[nt][r] = v;
        ss[r] += v * v;
      }
    }
    #pragma unroll
    for (int r = 0; r < 16; r++) {
      ss[r] += __shfl_xor(ss[r], 1, 64);
      ss[r] += __shfl_xor(ss[r], 2, 64);
      ss[r] += __shfl_xor(ss[r], 4, 64);
      ss[r] += __shfl_xor(ss[r], 8, 64);
      ss[r] += __shfl_xor(ss[r], 16, 64);
      float rms = rsqrtf(ss[r] * (1.0f / 128.0f) + 1e-5f) * (1.0f - LAMBDA_INIT);
      int m = (r & 3) + 8 * (r >> 2) + 4 * lh;
      #pragma unroll
      for (int nt = 0; nt < 4; nt++)
        attn[(long)(t0 + m) * EMB + h * 128 + nt * 32 + l32] = (f16)(o[nt][r] * rms);
    }
  }
}

// =====================================================================
extern "C" void kernel_launch(void* const* d_in, const int* in_sizes, int n_in,
                              void* d_out, int out_size, void* d_ws, size_t ws_size,
                              hipStream_t stream)
{
  (void)in_sizes; (void)n_in; (void)out_size; (void)ws_size;
  const float* x   = (const float*)d_in[0];
  const float* Wq  = (const float*)d_in[1];
  const float* Wk  = (const float*)d_in[2];
  const float* Wv  = (const float*)d_in[3];
  const float* Wo  = (const float*)d_in[4];
  const float* lq1 = (const float*)d_in[5];
  const float* lk1 = (const float*)d_in[6];
  const float* lq2 = (const float*)d_in[7];
  const float* lk2 = (const float*)d_in[8];
  float* out = (float*)d_out;

  const size_t TM = (size_t)T_SEQ * EMB;  // 2M elems
  const size_t WM = (size_t)EMB * EMB;    // 1M elems
  bf16* vtws = (bf16*)d_ws;          // 4MB
  f16*  aws  = (f16*)(vtws + TM);    // 4MB
  f16*  xf   = aws  + TM;            // 4MB
  f16*  wqf  = xf   + TM;            // 2MB
  f16*  wkf  = wqf  + WM;
  f16*  wvf  = wkf  + WM;
  f16*  wof  = wvf  + WM;
  f16*  qf   = wof  + WM;            // 4MB
  f16*  kf   = qf   + TM;            // 4MB

  convert_kernel<<<6144, 256, 0, stream>>>(x, Wq, Wk, Wv, Wo,
                                           xf, wqf, wkf, wvf, wof);
  qkv_gemm<<<384, 256, 0, stream>>>(xf, wqf, wkf, wvf, qf, kf, vtws);
  diff_attn<<<512, 256, 0, stream>>>(qf, kf, vtws, lq1, lk1, lq2, lk2, aws);
  out_gemm<<<256, 256, 0, stream>>>(aws, wof, out);
}

// Round 7
// 168.239 us; speedup vs baseline: 1.0764x; 1.0764x over previous
//
#include <hip/hip_runtime.h>
#include <hip/hip_bf16.h>

typedef __hip_bfloat16 bf16;
typedef _Float16 f16;
typedef __attribute__((ext_vector_type(8))) __bf16 bf16x8;
typedef __attribute__((ext_vector_type(8))) _Float16 f16x8;
typedef __attribute__((ext_vector_type(4))) _Float16 f16x4;
typedef __attribute__((ext_vector_type(4))) float floatx4;
typedef __attribute__((ext_vector_type(16))) float floatx16;

#define T_SEQ 2048
#define EMB   1024
#define LAMBDA_INIT 0.35550906759096926f

// round-to-nearest-even fp32 -> bf16
__device__ __forceinline__ bf16 f2bf(float f) {
  unsigned u;
  __builtin_memcpy(&u, &f, 4);
  u += 0x7FFF + ((u >> 16) & 1);
  unsigned short h = (unsigned short)(u >> 16);
  bf16 r;
  __builtin_memcpy(&r, &h, 2);
  return r;
}

// v_cvt_pk_bf16_f32: d[15:0]=bf16(lo), d[31:16]=bf16(hi)
__device__ __forceinline__ int cvtpk_bf16(float lo, float hi) {
  int r;
  asm("v_cvt_pk_bf16_f32 %0, %1, %2" : "=v"(r) : "v"(lo), "v"(hi));
  return r;
}

// v_permlane32_swap_b32: swaps a's upper-32-lane half with b's lower half.
__device__ __forceinline__ void permswap(int& a, int& b) {
  asm volatile("v_permlane32_swap_b32 %0, %1" : "+v"(a), "+v"(b));
}

__device__ __forceinline__ void gl_lds16(const void* g, void* l) {
  __builtin_amdgcn_global_load_lds((const __attribute__((address_space(1))) void*)g,
                                   (__attribute__((address_space(3))) void*)l, 16, 0, 0);
}

__device__ __forceinline__ floatx4 mfma_h(f16x8 a, f16x8 b, floatx4 c) {
  return __builtin_amdgcn_mfma_f32_16x16x32_f16(a, b, c, 0, 0, 0);
}
__device__ __forceinline__ floatx16 mfma32_h(f16x8 a, f16x8 b, floatx16 c) {
  return __builtin_amdgcn_mfma_f32_32x32x16_f16(a, b, c, 0, 0, 0);
}
__device__ __forceinline__ floatx16 mfma32_bf(bf16x8 a, bf16x8 b, floatx16 c) {
  return __builtin_amdgcn_mfma_f32_32x32x16_bf16(a, b, c, 0, 0, 0);
}

// =====================================================================
// fp32 -> fp16 conversion for x, Wq, Wk, Wv, Wo.
// =====================================================================
__global__ __launch_bounds__(256) void convert_kernel(
    const float* __restrict__ x,  const float* __restrict__ wq,
    const float* __restrict__ wk, const float* __restrict__ wv,
    const float* __restrict__ wo,
    f16* __restrict__ xf, f16* __restrict__ wqf, f16* __restrict__ wkf,
    f16* __restrict__ wvf, f16* __restrict__ wof)
{
  int b = blockIdx.x;
  const float* src; f16* dst; long off;
  if      (b < 2048) { src = x;  dst = xf;  off = (long)b * 1024; }
  else if (b < 3072) { src = wq; dst = wqf; off = (long)(b - 2048) * 1024; }
  else if (b < 4096) { src = wk; dst = wkf; off = (long)(b - 3072) * 1024; }
  else if (b < 5120) { src = wv; dst = wvf; off = (long)(b - 4096) * 1024; }
  else               { src = wo; dst = wof; off = (long)(b - 5120) * 1024; }
  long i = off + threadIdx.x * 4;
  float4 v = *(const float4*)(src + i);
  f16x4 o;
  o.x = (f16)v.x; o.y = (f16)v.y; o.z = (f16)v.z; o.w = (f16)v.w;
  *(f16x4*)(dst + i) = o;
}

// =====================================================================
// fp16 NT GEMM, 64x128 tile, BK=64, 24KB LDS staging (round-5 verified).
// Kld = row stride of A/B; Klen = K-extent to accumulate (K-split support).
// MODE 2 = RoPE-Q epilogue (fold 0.125) -> fp16; MODE 3 = RoPE-K (inv scale)
// MODE 0 = bf16 out (V);  MODE 1 = fp32 out (output-projection partial)
// =====================================================================
template <int MODE>
__device__ __forceinline__ void gemm64x128_f16(
    const f16* __restrict__ A_, const f16* __restrict__ B_,
    void* C0v, int Kld, int Klen, int ldc, int m0, int n0, char* smem)
{
  f16* As = (f16*)smem;              // 64 x 64 swz (8 KB)
  f16* Bs = (f16*)(smem + 8192);     // 128 x 64 swz (16 KB)
  const int tid  = threadIdx.x;
  const int wave = tid >> 6, lane = tid & 63, quad = lane >> 4, l16 = lane & 15;
  const int mo = (wave & 1) << 5;
  const int no = (wave >> 1) << 6;

  floatx4 acc[2][4];
  #pragma unroll
  for (int i = 0; i < 2; i++)
    #pragma unroll
    for (int j = 0; j < 4; j++) { acc[i][j][0]=0.f; acc[i][j][1]=0.f; acc[i][j][2]=0.f; acc[i][j][3]=0.f; }

  const int srow = tid >> 3;
  const int ch   = (tid & 7) ^ (srow & 7);
  const long aoff = (long)(m0 + srow) * Kld + ch * 8;
  const long boff = (long)(n0 + srow) * Kld + ch * 8;
  const int wb = wave << 10;

  for (int k0 = 0; k0 < Klen; k0 += 64) {
    #pragma unroll
    for (int rr = 0; rr < 2; rr++)
      gl_lds16(A_ + aoff + k0 + (long)rr * 32 * Kld, smem + wb + rr * 4096);
    #pragma unroll
    for (int rr = 0; rr < 4; rr++)
      gl_lds16(B_ + boff + k0 + (long)rr * 32 * Kld, smem + 8192 + wb + rr * 4096);
    __syncthreads();
    #pragma unroll
    for (int kt = 0; kt < 2; kt++) {
      f16x8 a[2], b[4];
      #pragma unroll
      for (int i = 0; i < 2; i++) {
        int m = mo + i * 16 + l16;
        a[i] = *(const f16x8*)(As + m * 64 + ((((kt << 2) | quad) ^ (m & 7)) << 3));
      }
      #pragma unroll
      for (int j = 0; j < 4; j++) {
        int n = no + j * 16 + l16;
        b[j] = *(const f16x8*)(Bs + n * 64 + ((((kt << 2) | quad) ^ (n & 7)) << 3));
      }
      #pragma unroll
      for (int i = 0; i < 2; i++)
        #pragma unroll
        for (int j = 0; j < 4; j++)
          acc[i][j] = mfma_h(a[i], b[j], acc[i][j]);
    }
    __syncthreads();
  }

  if (MODE == 1) {
    #pragma unroll
    for (int i = 0; i < 2; i++)
      #pragma unroll
      for (int j = 0; j < 4; j++)
        #pragma unroll
        for (int r = 0; r < 4; r++) {
          int row = m0 + mo + i * 16 + quad * 4 + r;
          int col = n0 + no + j * 16 + l16;
          ((float*)C0v)[(long)row * ldc + col] = acc[i][j][r];
        }
  } else {
    unsigned short* E = (unsigned short*)smem;   // 64x128 2-byte = 16 KB
    #pragma unroll
    for (int i = 0; i < 2; i++)
      #pragma unroll
      for (int j = 0; j < 4; j++)
        #pragma unroll
        for (int r = 0; r < 4; r++) {
          int row = mo + i * 16 + quad * 4 + r;
          int col = no + j * 16 + l16;
          float v = acc[i][j][r];
          unsigned short bits;
          if (MODE == 0) {
            bf16 t = f2bf(v);
            __builtin_memcpy(&bits, &t, 2);
          } else {
            float p = __shfl_xor(v, 1, 64);
            int d = col & 63;
            float fr = (float)(m0 + row) * __expf((float)(d >> 1) * -0.28782313662425574f);
            float sn, cs;
            sincosf(fr, &sn, &cs);
            float rot = (col & 1) ? fmaf(v, cs, p * sn) : fmaf(v, cs, -p * sn);
            float power = (float)(m0 + row - 1024) * (1.0f / 512.0f);
            if (MODE == 3) power = -power;
            float sv = fmaf(2.0f, (float)(d & 31), 25.6f) * (1.0f / 89.6f);
            float s = __expf(power * __logf(sv));
            float ov = rot * s;
            if (MODE == 2) ov *= 0.125f;
            f16 t = (f16)ov;
            __builtin_memcpy(&bits, &t, 2);
          }
          E[row * 128 + col] = bits;
        }
    __syncthreads();
    const int rr0 = tid >> 4;
    const int c8  = (tid & 15) * 8;
    #pragma unroll
    for (int p2 = 0; p2 < 4; p2++) {
      int row = p2 * 16 + rr0;
      *(uint4*)((unsigned short*)C0v + (long)(m0 + row) * ldc + n0 + c8) =
          *(const uint4*)(E + row * 128 + c8);
    }
  }
}

__global__ __launch_bounds__(256) void qkv_gemm(
    const f16* __restrict__ xf,
    const f16* __restrict__ wqf, const f16* __restrict__ wkf,
    const f16* __restrict__ wvf,
    f16* __restrict__ qf, f16* __restrict__ kf, bf16* __restrict__ vt)
{
  __shared__ char smem[24576];
  int bid = blockIdx.x;
  if (bid < 256) {
    gemm64x128_f16<2>(xf, wqf, qf, 1024, 1024, 1024, (bid >> 3) * 64, (bid & 7) * 128, smem);
  } else if (bid < 512) {
    bid -= 256;
    gemm64x128_f16<3>(xf, wkf, kf, 1024, 1024, 1024, (bid >> 3) * 64, (bid & 7) * 128, smem);
  } else {
    bid -= 512;
    gemm64x128_f16<0>(wvf, xf, vt, 1024, 1024, 2048, (bid >> 4) * 64, (bid & 15) * 128, smem);
  }
}

// out_gemm K-split by 2: 512 blocks (2/CU) each accumulate a 64x128 fp32
// partial over half of K; add_out merges. Fixes the 256-block = 1-block/CU
// starvation of the old out_gemm (no cross-block overlap of staging stalls).
__global__ __launch_bounds__(256) void out_gemm(const f16* __restrict__ attn,
                                                const f16* __restrict__ Wo,
                                                float* __restrict__ p0,
                                                float* __restrict__ p1)
{
  __shared__ char smem[24576];
  int bid = blockIdx.x;
  const int kh = bid >> 8;       // K-half 0/1
  const int b  = bid & 255;
  float* pb = kh ? p1 : p0;
  gemm64x128_f16<1>(attn + kh * 512, Wo + kh * 512, pb, 1024, 512, 1024,
                    (b >> 3) * 64, (b & 7) * 128, smem);
}

__global__ __launch_bounds__(256) void add_out(const float* __restrict__ p0,
                                               const float* __restrict__ p1,
                                               float* __restrict__ out)
{
  long i = ((long)blockIdx.x * 256 + threadIdx.x) * 4;
  float4 a = *(const float4*)(p0 + i);
  float4 b = *(const float4*)(p1 + i);
  float4 c;
  c.x = a.x + b.x; c.y = a.y + b.y; c.z = a.z + b.z; c.w = a.w + b.w;
  *(float4*)(out + i) = c;
}

// =====================================================================
// Differential flash attention — register-staged single-barrier edition
// (round-5 structure, unchanged; best measured 51.0 µs).
// =====================================================================
__global__ __launch_bounds__(256) void diff_attn(
    const f16* __restrict__ qf_, const f16* __restrict__ kf_,
    const bf16* __restrict__ vt,
    const float* __restrict__ lq1, const float* __restrict__ lk1,
    const float* __restrict__ lq2, const float* __restrict__ lk2,
    f16* __restrict__ attn)
{
  __shared__ char smem[65536];
  // buf b at b*32768: K0 @0 (8KB) | K1 @8192 (8KB) | V @16384 (16KB)
  const int tid  = threadIdx.x;
  const int wave = tid >> 6, lane = tid & 63;
  const int l32 = lane & 31, lh = lane >> 5;
  const int h  = blockIdx.x & 7;         // head pair — XCD-affine
  const int qb = blockIdx.x >> 3;        // q block 0..63 (32 rows each)
  const int hl = wave >> 1;              // head in pair
  const int ws = wave & 1;               // key-half of this wave
  const int hh = h * 2 + hl;
  const int t0 = qb * 32;

  float a1 = lq1[lane] * lk1[lane];
  float a2 = lq2[lane] * lk2[lane];
  #pragma unroll
  for (int off = 1; off < 64; off <<= 1) {
    a1 += __shfl_xor(a1, off, 64);
    a2 += __shfl_xor(a2, off, 64);
  }
  const float lam = __expf(a1) - __expf(a2) + LAMBDA_INIT;

  // Q B-frags (32 rows x 64 d): n=query=l32, k = kt*16 + lh*8 + j
  f16x8 qfr[4];
  {
    const f16* qrow = qf_ + (long)(t0 + l32) * EMB + hh * 64 + lh * 8;
    #pragma unroll
    for (int kt = 0; kt < 4; kt++) qfr[kt] = *(const f16x8*)(qrow + kt * 16);
  }

  floatx16 o[4];   // nt over Dv=128, un-normalized accumulation
  #pragma unroll
  for (int nt = 0; nt < 4; nt++)
    #pragma unroll
    for (int r = 0; r < 16; r++) o[nt][r] = 0.f;
  // denominator partials: 4-way tree to cut the serial add chain
  float lr0 = 0.f, lr1 = 0.f, lr2 = 0.f, lr3 = 0.f;

  // staging: waves 0,1 -> K0,K1; waves 2,3 -> V halves
  const int srow = lane >> 3;
  const int ch   = (lane & 7) ^ srow;
  const f16*  kgp = kf_ + (long)(h * 2 + ws) * 64 + (long)srow * EMB + ch * 8;
  const bf16* vgp = vt + (long)(h * 128 + (wave - 2) * 64 + srow) * T_SEQ + ch * 8;
  const int kofs = wave * 8192;                 // waves 0,1
  const int vofs = 16384 + (wave - 2) * 8192;   // waves 2,3

  // prologue: stage tile 0 into buffer 0
  if (wave < 2) {
    #pragma unroll
    for (int j = 0; j < 8; j++)
      gl_lds16(kgp + (long)j * 8 * EMB, smem + kofs + j * 1024);
  } else {
    #pragma unroll
    for (int j = 0; j < 8; j++)
      gl_lds16(vgp + (long)j * 8 * T_SEQ, smem + vofs + j * 1024);
  }

  for (int kb = 0; kb < T_SEQ; kb += 64) {
    const int cur = (kb >> 6) & 1;
    const char* sb = smem + cur * 32768;

    // own tile-i loads were issued a full iteration ago -> no stall
    asm volatile("s_waitcnt vmcnt(0)" ::: "memory");
    // all waves' tile-i loads landed; all waves left iter i-1
    asm volatile("s_barrier" ::: "memory");

    const f16*  Ks  = (const f16*)(sb + hl * 8192);
    const bf16* Vsb = (const bf16*)(sb + 16384);

    // ---- register staging: ALL ds_reads before any gl_lds issue ----
    f16x8 kfr[4];
    #pragma unroll
    for (int kt = 0; kt < 4; kt++) {
      int krow = ws * 32 + l32;
      int c = kt * 2 + lh;
      kfr[kt] = *(const f16x8*)(Ks + krow * 64 + ((c ^ (krow & 7)) << 3));
    }
    bf16x8 vfr[4][2];
    #pragma unroll
    for (int nt = 0; nt < 4; nt++) {
      #pragma unroll
      for (int kt = 0; kt < 2; kt++) {
        int vrow = nt * 32 + l32;
        int c = ws * 4 + kt * 2 + lh;
        vfr[nt][kt] = *(const bf16x8*)(Vsb + vrow * 64 + ((c ^ (vrow & 7)) << 3));
      }
    }

    // ---- prefetch issue (after all ds_reads in program order) ----
    if (kb + 64 < T_SEQ) {
      char* nb = smem + (cur ^ 1) * 32768;
      if (wave < 2) {
        #pragma unroll
        for (int j = 0; j < 8; j++)
          gl_lds16(kgp + (long)(kb + 64) * EMB + (long)j * 8 * EMB,
                   nb + kofs + j * 1024);
      } else {
        #pragma unroll
        for (int j = 0; j < 8; j++)
          gl_lds16(vgp + (kb + 64) + (long)j * 8 * T_SEQ,
                   nb + vofs + j * 1024);
      }
    }

    // ---- compute: pure registers from here ----
    // QK^T swapped: A=K (m=key=l32 of own half), B=Q (n=query=l32)
    floatx16 s;
    #pragma unroll
    for (int r = 0; r < 16; r++) s[r] = 0.f;
    #pragma unroll
    for (int kt = 0; kt < 4; kt++)
      s = mfma32_h(kfr[kt], qfr[kt], s);
    // static-offset softmax; denominator partials in a 4-way tree
    #pragma unroll
    for (int r = 0; r < 4; r++) {
      float p0 = __builtin_amdgcn_exp2f(
          fmaf(s[r], 1.4426950408889634f, -17.312340490667562f));
      float p1 = __builtin_amdgcn_exp2f(
          fmaf(s[r + 4], 1.4426950408889634f, -17.312340490667562f));
      float p2 = __builtin_amdgcn_exp2f(
          fmaf(s[r + 8], 1.4426950408889634f, -17.312340490667562f));
      float p3 = __builtin_amdgcn_exp2f(
          fmaf(s[r + 12], 1.4426950408889634f, -17.312340490667562f));
      s[r] = p0; s[r + 4] = p1; s[r + 8] = p2; s[r + 12] = p3;
      lr0 += p0; lr1 += p1; lr2 += p2; lr3 += p3;
    }
    // in-register P -> bf16 A-frags (cvt_pk + permlane32_swap)
    bf16x8 pf[2];
    #pragma unroll
    for (int kt = 0; kt < 2; kt++) {
      const int b0 = kt * 8;
      int w0 = cvtpk_bf16(s[b0 + 0], s[b0 + 1]);
      int w1 = cvtpk_bf16(s[b0 + 2], s[b0 + 3]);
      int w2 = cvtpk_bf16(s[b0 + 4], s[b0 + 5]);
      int w3 = cvtpk_bf16(s[b0 + 6], s[b0 + 7]);
      permswap(w0, w2);
      permswap(w1, w3);
      union { int i[4]; bf16x8 v; } u;
      u.i[0] = w0; u.i[1] = w1; u.i[2] = w2; u.i[3] = w3;
      pf[kt] = u.v;
    }
    // PV: O += P V over own keys (register V frags)
    #pragma unroll
    for (int nt = 0; nt < 4; nt++) {
      #pragma unroll
      for (int kt = 0; kt < 2; kt++)
        o[nt] = mfma32_bf(pf[kt], vfr[nt][kt], o[nt]);
    }
  }
  __syncthreads();   // loop exit sync before epilogue overwrites smem

  float lr = (lr0 + lr1) + (lr2 + lr3);
  // merge lh halves: lrw = this wave's full 32-key denominator for query l32
  float lrw = lr + __shfl_xor(lr, 32, 64);

  float* Cb = (float*)smem;                  // 2 heads x 32x128 fp32 = 32KB
  float* Lb = (float*)(smem + 32768);        // 128 denominator partials

  // phase 1: key-half ws==1 publishes raw O; all waves publish lrw
  if (ws == 1) {
    #pragma unroll
    for (int r = 0; r < 16; r++) {
      int m = (r & 3) + 8 * (r >> 2) + 4 * lh;
      #pragma unroll
      for (int nt = 0; nt < 4; nt++)
        Cb[hl * 4096 + m * 128 + nt * 32 + l32] = o[nt][r];
    }
  }
  if (lh == 0) Lb[ws * 64 + hl * 32 + l32] = lrw;
  __syncthreads();
  // phase 2: ws==0 merges halves and normalizes
  if (ws == 0) {
    #pragma unroll
    for (int r = 0; r < 16; r++) {
      int m = (r & 3) + 8 * (r >> 2) + 4 * lh;
      float inv = 1.0f / (Lb[hl * 32 + m] + Lb[64 + hl * 32 + m]);
      #pragma unroll
      for (int nt = 0; nt < 4; nt++)
        o[nt][r] = (o[nt][r] + Cb[hl * 4096 + m * 128 + nt * 32 + l32]) * inv;
    }
  }
  __syncthreads();
  // phase 3: head1 publishes normalized O1
  if (hl == 1 && ws == 0) {
    #pragma unroll
    for (int r = 0; r < 16; r++) {
      int m = (r & 3) + 8 * (r >> 2) + 4 * lh;
      #pragma unroll
      for (int nt = 0; nt < 4; nt++)
        Cb[4096 + m * 128 + nt * 32 + l32] = o[nt][r];
    }
  }
  __syncthreads();
  // phase 4: head0 does diff + rms-norm + store
  if (hl == 0 && ws == 0) {
    float ss[16];
    #pragma unroll
    for (int r = 0; r < 16; r++) {
      int m = (r & 3) + 8 * (r >> 2) + 4 * lh;
      ss[r] = 0.f;
      #pragma unroll
      for (int nt = 0; nt < 4; nt++) {
        float v = o[nt][r] - lam * Cb[4096 + m * 128 + nt * 32 + l32];
        o[nt][r] = v;
        ss[r] += v * v;
      }
    }
    #pragma unroll
    for (int r = 0; r < 16; r++) {
      ss[r] += __shfl_xor(ss[r], 1, 64);
      ss[r] += __shfl_xor(ss[r], 2, 64);
      ss[r] += __shfl_xor(ss[r], 4, 64);
      ss[r] += __shfl_xor(ss[r], 8, 64);
      ss[r] += __shfl_xor(ss[r], 16, 64);
      float rms = rsqrtf(ss[r] * (1.0f / 128.0f) + 1e-5f) * (1.0f - LAMBDA_INIT);
      int m = (r & 3) + 8 * (r >> 2) + 4 * lh;
      #pragma unroll
      for (int nt = 0; nt < 4; nt++)
        attn[(long)(t0 + m) * EMB + h * 128 + nt * 32 + l32] = (f16)(o[nt][r] * rms);
    }
  }
}

// =====================================================================
extern "C" void kernel_launch(void* const* d_in, const int* in_sizes, int n_in,
                              void* d_out, int out_size, void* d_ws, size_t ws_size,
                              hipStream_t stream)
{
  (void)in_sizes; (void)n_in; (void)out_size; (void)ws_size;
  const float* x   = (const float*)d_in[0];
  const float* Wq  = (const float*)d_in[1];
  const float* Wk  = (const float*)d_in[2];
  const float* Wv  = (const float*)d_in[3];
  const float* Wo  = (const float*)d_in[4];
  const float* lq1 = (const float*)d_in[5];
  const float* lk1 = (const float*)d_in[6];
  const float* lq2 = (const float*)d_in[7];
  const float* lk2 = (const float*)d_in[8];
  float* out = (float*)d_out;

  const size_t TM = (size_t)T_SEQ * EMB;  // 2M elems
  const size_t WM = (size_t)EMB * EMB;    // 1M elems
  bf16* vtws = (bf16*)d_ws;          // 4MB      @ 0
  f16*  aws  = (f16*)(vtws + TM);    // 4MB      @ 4MB
  f16*  xf   = aws  + TM;            // 4MB      @ 8MB
  f16*  wqf  = xf   + TM;            // 2MB      @ 12MB
  f16*  wkf  = wqf  + WM;            //          @ 14MB
  f16*  wvf  = wkf  + WM;            //          @ 16MB
  f16*  wof  = wvf  + WM;            //          @ 18MB
  f16*  qf   = wof  + WM;            // 4MB      @ 20MB
  f16*  kf   = qf   + TM;            // 4MB      @ 24MB

  // K-split partials REUSE dead regions (zero extra workspace):
  //  p0 (8MB fp32) over xf+wqf+wkf  — dead after qkv_gemm
  //  p1 (8MB fp32) over qf+kf       — dead after diff_attn
  float* p0 = (float*)xf;
  float* p1 = (float*)qf;

  convert_kernel<<<6144, 256, 0, stream>>>(x, Wq, Wk, Wv, Wo,
                                           xf, wqf, wkf, wvf, wof);
  qkv_gemm<<<768, 256, 0, stream>>>(xf, wqf, wkf, wvf, qf, kf, vtws);
  diff_attn<<<512, 256, 0, stream>>>(qf, kf, vtws, lq1, lk1, lq2, lk2, aws);
  out_gemm<<<512, 256, 0, stream>>>(aws, wof, p0, p1);
  add_out<<<2048, 256, 0, stream>>>(p0, p1, out);
}